// Round 3
// baseline (339.582 us; speedup 1.0000x reference)
//
#include <hip/hip_runtime.h>

static constexpr int CCOLS = 50257;
static constexpr int BROWS = 4096;
static constexpr int TPB   = 256;

typedef float f32x4 __attribute__((ext_vector_type(4)));

// One block per row: online-softmax logsumexp + windowed gather dot.
// Unroll-by-2 with two independent (m,s) chains -> 2 loads in flight/thread.
// Last-finishing block performs the final mean (fence+counter pattern), so
// there is no second kernel launch.
__global__ __launch_bounds__(TPB) void row_loss_kernel(
    const float* __restrict__ preds,
    const int*   __restrict__ labels,
    const float* __restrict__ window,
    int L,
    float* __restrict__ row_loss,     // d_ws: BROWS floats
    unsigned*  __restrict__ counter,  // d_ws + BROWS*4: zeroed by memset node
    float* __restrict__ out)
{
    const int row = blockIdx.x;
    const size_t base = (size_t)row * CCOLS;
    const float* __restrict__ p = preds + base;
    const int tid = threadIdx.x;

    float m0 = -1.0e30f, s0 = 0.0f;   // finite sentinel: avoids exp(-inf - -inf)
    float m1 = -1.0e30f, s1 = 0.0f;

    // Row base alignment: base % 4 == row % 4 (50257 mod 4 == 1). Align for float4.
    const int head = (int)((4 - (base & 3)) & 3);
    const int nvec = (CCOLS - head) >> 2;
    const int tail_start = head + nvec * 4;

    const f32x4* __restrict__ p4 = (const f32x4*)(p + head);

    int i = tid;
    for (; i + TPB < nvec; i += 2 * TPB) {
        f32x4 a = __builtin_nontemporal_load(p4 + i);
        f32x4 b = __builtin_nontemporal_load(p4 + i + TPB);
        float am = fmaxf(fmaxf(a[0], a[1]), fmaxf(a[2], a[3]));
        float bm = fmaxf(fmaxf(b[0], b[1]), fmaxf(b[2], b[3]));
        if (am > m0) { s0 *= __expf(m0 - am); m0 = am; }
        if (bm > m1) { s1 *= __expf(m1 - bm); m1 = bm; }
        s0 += __expf(a[0] - m0) + __expf(a[1] - m0) + __expf(a[2] - m0) + __expf(a[3] - m0);
        s1 += __expf(b[0] - m1) + __expf(b[1] - m1) + __expf(b[2] - m1) + __expf(b[3] - m1);
    }
    for (; i < nvec; i += TPB) {
        f32x4 a = __builtin_nontemporal_load(p4 + i);
        float am = fmaxf(fmaxf(a[0], a[1]), fmaxf(a[2], a[3]));
        if (am > m0) { s0 *= __expf(m0 - am); m0 = am; }
        s0 += __expf(a[0] - m0) + __expf(a[1] - m0) + __expf(a[2] - m0) + __expf(a[3] - m0);
    }

    // Merge the two chains.
    float m = fmaxf(m0, m1);
    float s = s0 * __expf(m0 - m) + s1 * __expf(m1 - m);

    if (tid == 0) {
        for (int k = 0; k < head; ++k) {
            float x = p[k];
            if (x > m) { s *= __expf(m - x); m = x; }
            s += __expf(x - m);
        }
        for (int k = tail_start; k < CCOLS; ++k) {
            float x = p[k];
            if (x > m) { s *= __expf(m - x); m = x; }
            s += __expf(x - m);
        }
    }

    // Wave-64 shfl_down reduce of (m, s) online pairs.
    for (int off = 32; off > 0; off >>= 1) {
        float mo = __shfl_down(m, off);
        float so = __shfl_down(s, off);
        float mn = fmaxf(m, mo);
        s = s * __expf(m - mn) + so * __expf(mo - mn);
        m = mn;
    }

    __shared__ float sm[TPB / 64], ss[TPB / 64];
    const int wave = tid >> 6, lane = tid & 63;
    if (lane == 0) { sm[wave] = m; ss[wave] = s; }
    __syncthreads();

    __shared__ int is_last;
    if (tid == 0) {
        m = sm[0]; s = ss[0];
        #pragma unroll
        for (int w = 1; w < TPB / 64; ++w) {
            float mo = sm[w], so = ss[w];
            float mn = fmaxf(m, mo);
            s = s * __expf(m - mn) + so * __expf(mo - mn);
            m = mn;
        }
        // Windowed dot around the label; window truncated (not renormalized) at edges.
        const int lab  = labels[row];
        const int half = L >> 1;
        float dot = 0.0f, wsum = 0.0f;
        for (int k = 0; k < L; ++k) {
            int pos = lab + k - half;
            if (pos >= 0 && pos < CCOLS) {
                float w = window[k];
                dot = fmaf(w, p[pos], dot);
                wsum += w;
            }
        }
        row_loss[row] = wsum * (m + __logf(s)) - dot;
        // Release: rl store above becomes agent-visible before the counter bump.
        unsigned old = __hip_atomic_fetch_add(counter, 1u, __ATOMIC_ACQ_REL,
                                              __HIP_MEMORY_SCOPE_AGENT);
        is_last = (old == (unsigned)(BROWS - 1));
    }
    __syncthreads();

    // The last block to finish reduces all row losses in a fixed order.
    if (is_last) {
        __shared__ float buf[TPB];
        float acc = 0.0f;
        for (int k = tid; k < BROWS; k += TPB) acc += row_loss[k];
        buf[tid] = acc;
        __syncthreads();
        for (int off = TPB / 2; off > 0; off >>= 1) {
            if (tid < off) buf[tid] += buf[tid + off];
            __syncthreads();
        }
        if (tid == 0) out[0] = buf[0] / (float)BROWS;
    }
}

extern "C" void kernel_launch(void* const* d_in, const int* in_sizes, int n_in,
                              void* d_out, int out_size, void* d_ws, size_t ws_size,
                              hipStream_t stream)
{
    const float* preds  = (const float*)d_in[0];
    const int*   labels = (const int*)d_in[1];
    const float* window = (const float*)d_in[2];
    const int L = in_sizes[2];

    float*    out = (float*)d_out;
    float*    rl  = (float*)d_ws;                    // BROWS per-row losses
    unsigned* cnt = (unsigned*)((char*)d_ws + BROWS * sizeof(float));

    hipMemsetAsync(cnt, 0, sizeof(unsigned), stream);  // graph-capturable node
    row_loss_kernel<<<BROWS, TPB, 0, stream>>>(preds, labels, window, L, rl, cnt, out);
}

// Round 4
// 146.560 us; speedup vs baseline: 2.3170x; 2.3170x over previous
//
#include <hip/hip_runtime.h>

static constexpr int CCOLS = 50257;
static constexpr int BROWS = 4096;
static constexpr int TPB   = 256;
static constexpr int NGRP  = BROWS / 64;   // 64 groups of 64 rows

typedef float f32x4 __attribute__((ext_vector_type(4)));

#define AGENT __HIP_MEMORY_SCOPE_AGENT

// One block per row: online-softmax logsumexp + windowed gather dot.
// Fused final mean via RELAXED agent-scope atomics only (no acquire/release
// fences -> no buffer_wbl2/buffer_inv L2 tag-walks, which cost +200us in R3).
// Visibility: sc0/sc1 (device-coherent) stores + s_waitcnt vmcnt(0) before the
// counter bump; readers use device-coherent relaxed atomic loads.
__global__ __launch_bounds__(TPB) void row_loss_kernel(
    const float* __restrict__ preds,
    const int*   __restrict__ labels,
    const float* __restrict__ window,
    int L,
    float*    __restrict__ rl,        // [BROWS] per-row losses
    float*    __restrict__ partials,  // [NGRP] per-group sums
    unsigned* __restrict__ gcnt,      // [NGRP*16] strided group counters (zeroed)
    unsigned* __restrict__ fcnt,      // [1] final counter (zeroed)
    float*    __restrict__ out)
{
    const int row = blockIdx.x;
    const size_t base = (size_t)row * CCOLS;
    const float* __restrict__ p = preds + base;
    const int tid = threadIdx.x;

    float m0 = -1.0e30f, s0 = 0.0f;   // finite sentinel: avoids exp(-inf - -inf)
    float m1 = -1.0e30f, s1 = 0.0f;

    // Row base alignment: base % 4 == row % 4 (50257 mod 4 == 1). Align for float4.
    const int head = (int)((4 - (base & 3)) & 3);
    const int nvec = (CCOLS - head) >> 2;
    const int tail_start = head + nvec * 4;

    const f32x4* __restrict__ p4 = (const f32x4*)(p + head);

    int i = tid;
    for (; i + TPB < nvec; i += 2 * TPB) {
        f32x4 a = __builtin_nontemporal_load(p4 + i);
        f32x4 b = __builtin_nontemporal_load(p4 + i + TPB);
        float am = fmaxf(fmaxf(a[0], a[1]), fmaxf(a[2], a[3]));
        float bm = fmaxf(fmaxf(b[0], b[1]), fmaxf(b[2], b[3]));
        if (am > m0) { s0 *= __expf(m0 - am); m0 = am; }
        if (bm > m1) { s1 *= __expf(m1 - bm); m1 = bm; }
        s0 += __expf(a[0] - m0) + __expf(a[1] - m0) + __expf(a[2] - m0) + __expf(a[3] - m0);
        s1 += __expf(b[0] - m1) + __expf(b[1] - m1) + __expf(b[2] - m1) + __expf(b[3] - m1);
    }
    for (; i < nvec; i += TPB) {
        f32x4 a = __builtin_nontemporal_load(p4 + i);
        float am = fmaxf(fmaxf(a[0], a[1]), fmaxf(a[2], a[3]));
        if (am > m0) { s0 *= __expf(m0 - am); m0 = am; }
        s0 += __expf(a[0] - m0) + __expf(a[1] - m0) + __expf(a[2] - m0) + __expf(a[3] - m0);
    }

    // Merge the two chains.
    float m = fmaxf(m0, m1);
    float s = s0 * __expf(m0 - m) + s1 * __expf(m1 - m);

    if (tid == 0) {
        for (int k = 0; k < head; ++k) {
            float x = p[k];
            if (x > m) { s *= __expf(m - x); m = x; }
            s += __expf(x - m);
        }
        for (int k = tail_start; k < CCOLS; ++k) {
            float x = p[k];
            if (x > m) { s *= __expf(m - x); m = x; }
            s += __expf(x - m);
        }
    }

    // Wave-64 shfl_down reduce of (m, s) online pairs.
    for (int off = 32; off > 0; off >>= 1) {
        float mo = __shfl_down(m, off);
        float so = __shfl_down(s, off);
        float mn = fmaxf(m, mo);
        s = s * __expf(m - mn) + so * __expf(mo - mn);
        m = mn;
    }

    __shared__ float sm[TPB / 64], ss[TPB / 64];
    const int wave = tid >> 6, lane = tid & 63;
    if (lane == 0) { sm[wave] = m; ss[wave] = s; }
    __syncthreads();

    if (tid >= 64) return;   // epilogue runs entirely in wave 0

    int glast = 0;
    if (tid == 0) {
        m = sm[0]; s = ss[0];
        #pragma unroll
        for (int w = 1; w < TPB / 64; ++w) {
            float mo = sm[w], so = ss[w];
            float mn = fmaxf(m, mo);
            s = s * __expf(m - mn) + so * __expf(mo - mn);
            m = mn;
        }
        // Windowed dot around the label; window truncated (not renormalized).
        const int lab  = labels[row];
        const int half = L >> 1;
        float dot = 0.0f, wsum = 0.0f;
        for (int k = 0; k < L; ++k) {
            int pos = lab + k - half;
            if (pos >= 0 && pos < CCOLS) {
                float w = window[k];
                dot = fmaf(w, p[pos], dot);
                wsum += w;
            }
        }
        float v = wsum * (m + __logf(s)) - dot;
        // Device-coherent (sc0/sc1) store; no cache maintenance emitted.
        __hip_atomic_store(&rl[row], v, __ATOMIC_RELAXED, AGENT);
        // Make the store reach the coherence point before the counter bump.
        asm volatile("s_waitcnt vmcnt(0)" ::: "memory");
        unsigned og = __hip_atomic_fetch_add(&gcnt[(row >> 6) * 16], 1u,
                                             __ATOMIC_RELAXED, AGENT);
        glast = (og == 63u);
    }

    // Group-last block: wave 0 reduces its group's 64 row losses (fixed order).
    if (__shfl(glast, 0)) {
        const int gbase = row & ~63;
        float x = __hip_atomic_load(&rl[gbase + tid], __ATOMIC_RELAXED, AGENT);
        for (int off = 32; off > 0; off >>= 1) x += __shfl_down(x, off);
        int flast = 0;
        if (tid == 0) {
            __hip_atomic_store(&partials[row >> 6], x, __ATOMIC_RELAXED, AGENT);
            asm volatile("s_waitcnt vmcnt(0)" ::: "memory");
            unsigned of = __hip_atomic_fetch_add(fcnt, 1u, __ATOMIC_RELAXED, AGENT);
            flast = (of == (unsigned)(NGRP - 1));
        }
        // Final block: reduce the 64 group partials (fixed order), write mean.
        if (__shfl(flast, 0)) {
            float y = __hip_atomic_load(&partials[tid], __ATOMIC_RELAXED, AGENT);
            for (int off = 32; off > 0; off >>= 1) y += __shfl_down(y, off);
            if (tid == 0) out[0] = y / (float)BROWS;
        }
    }
}

extern "C" void kernel_launch(void* const* d_in, const int* in_sizes, int n_in,
                              void* d_out, int out_size, void* d_ws, size_t ws_size,
                              hipStream_t stream)
{
    const float* preds  = (const float*)d_in[0];
    const int*   labels = (const int*)d_in[1];
    const float* window = (const float*)d_in[2];
    const int L = in_sizes[2];

    float* out = (float*)d_out;
    char*  ws  = (char*)d_ws;
    // Layout: rl[4096] | partials[64] | gcnt[64*16 strided] | fcnt[1]
    float*    rl       = (float*)ws;                          // 16384 B
    float*    partials = (float*)(ws + 16384);                //   256 B
    unsigned* gcnt     = (unsigned*)(ws + 16640);             //  4096 B (64 x 64B stride)
    unsigned* fcnt     = (unsigned*)(ws + 16640 + 4096);      //     4 B

    // Zero all counters (single graph-capturable node).
    hipMemsetAsync(gcnt, 0, 4096 + 4, stream);
    row_loss_kernel<<<BROWS, TPB, 0, stream>>>(preds, labels, window, L,
                                               rl, partials, gcnt, fcnt, out);
}

// Round 5
// 138.523 us; speedup vs baseline: 2.4514x; 1.0580x over previous
//
#include <hip/hip_runtime.h>

static constexpr int CCOLS = 50257;
static constexpr int BROWS = 4096;
static constexpr int TPB   = 256;

typedef float f32x4 __attribute__((ext_vector_type(4)));

// One block per row: online-softmax logsumexp + windowed gather dot.
// Unroll-by-2 with two independent (m,s) chains -> 2 loads in flight/thread.
// R3 (acq-rel fused reduce, +200us: L2 wbl2/inv storm) and R4 (relaxed-atomic
// hierarchical fused reduce, +8us: memset node + serialized coherent tail)
// both lost to this plain two-kernel structure. Row kernel streams at ~6.24
// TB/s = 99% of the measured 6.29 TB/s achievable ceiling.
__global__ __launch_bounds__(TPB) void row_loss_kernel(
    const float* __restrict__ preds,
    const int*   __restrict__ labels,
    const float* __restrict__ window,
    int L,
    float* __restrict__ row_loss)
{
    const int row = blockIdx.x;
    const size_t base = (size_t)row * CCOLS;
    const float* __restrict__ p = preds + base;
    const int tid = threadIdx.x;

    float m0 = -1.0e30f, s0 = 0.0f;   // finite sentinel: avoids exp(-inf - -inf)
    float m1 = -1.0e30f, s1 = 0.0f;

    // Row base alignment: base % 4 == row % 4 (50257 mod 4 == 1). Align for float4.
    const int head = (int)((4 - (base & 3)) & 3);
    const int nvec = (CCOLS - head) >> 2;
    const int tail_start = head + nvec * 4;

    const f32x4* __restrict__ p4 = (const f32x4*)(p + head);

    int i = tid;
    for (; i + TPB < nvec; i += 2 * TPB) {
        f32x4 a = __builtin_nontemporal_load(p4 + i);
        f32x4 b = __builtin_nontemporal_load(p4 + i + TPB);
        float am = fmaxf(fmaxf(a[0], a[1]), fmaxf(a[2], a[3]));
        float bm = fmaxf(fmaxf(b[0], b[1]), fmaxf(b[2], b[3]));
        if (am > m0) { s0 *= __expf(m0 - am); m0 = am; }
        if (bm > m1) { s1 *= __expf(m1 - bm); m1 = bm; }
        s0 += __expf(a[0] - m0) + __expf(a[1] - m0) + __expf(a[2] - m0) + __expf(a[3] - m0);
        s1 += __expf(b[0] - m1) + __expf(b[1] - m1) + __expf(b[2] - m1) + __expf(b[3] - m1);
    }
    for (; i < nvec; i += TPB) {
        f32x4 a = __builtin_nontemporal_load(p4 + i);
        float am = fmaxf(fmaxf(a[0], a[1]), fmaxf(a[2], a[3]));
        if (am > m0) { s0 *= __expf(m0 - am); m0 = am; }
        s0 += __expf(a[0] - m0) + __expf(a[1] - m0) + __expf(a[2] - m0) + __expf(a[3] - m0);
    }

    // Merge the two chains.
    float m = fmaxf(m0, m1);
    float s = s0 * __expf(m0 - m) + s1 * __expf(m1 - m);

    if (tid == 0) {
        for (int k = 0; k < head; ++k) {
            float x = p[k];
            if (x > m) { s *= __expf(m - x); m = x; }
            s += __expf(x - m);
        }
        for (int k = tail_start; k < CCOLS; ++k) {
            float x = p[k];
            if (x > m) { s *= __expf(m - x); m = x; }
            s += __expf(x - m);
        }
    }

    // Wave-64 shfl_down reduce of (m, s) online pairs.
    for (int off = 32; off > 0; off >>= 1) {
        float mo = __shfl_down(m, off);
        float so = __shfl_down(s, off);
        float mn = fmaxf(m, mo);
        s = s * __expf(m - mn) + so * __expf(mo - mn);
        m = mn;
    }

    __shared__ float sm[TPB / 64], ss[TPB / 64];
    const int wave = tid >> 6, lane = tid & 63;
    if (lane == 0) { sm[wave] = m; ss[wave] = s; }
    __syncthreads();

    if (tid == 0) {
        m = sm[0]; s = ss[0];
        #pragma unroll
        for (int w = 1; w < TPB / 64; ++w) {
            float mo = sm[w], so = ss[w];
            float mn = fmaxf(m, mo);
            s = s * __expf(m - mn) + so * __expf(mo - mn);
            m = mn;
        }
        // Windowed dot around the label; window truncated (not renormalized) at edges.
        const int lab  = labels[row];
        const int half = L >> 1;
        float dot = 0.0f, wsum = 0.0f;
        for (int k = 0; k < L; ++k) {
            int pos = lab + k - half;
            if (pos >= 0 && pos < CCOLS) {
                float w = window[k];
                dot = fmaf(w, p[pos], dot);
                wsum += w;
            }
        }
        row_loss[row] = wsum * (m + __logf(s)) - dot;
    }
}

// Deterministic fixed-order reduction: per-thread strided sum + LDS tree.
__global__ __launch_bounds__(256) void reduce_kernel(
    const float* __restrict__ row_loss, float* __restrict__ out, int n)
{
    __shared__ float buf[256];
    float acc = 0.0f;
    for (int i = threadIdx.x; i < n; i += 256) acc += row_loss[i];
    buf[threadIdx.x] = acc;
    __syncthreads();
    for (int off = 128; off > 0; off >>= 1) {
        if ((int)threadIdx.x < off) buf[threadIdx.x] += buf[threadIdx.x + off];
        __syncthreads();
    }
    if (threadIdx.x == 0) out[0] = buf[0] / (float)n;
}

extern "C" void kernel_launch(void* const* d_in, const int* in_sizes, int n_in,
                              void* d_out, int out_size, void* d_ws, size_t ws_size,
                              hipStream_t stream)
{
    const float* preds  = (const float*)d_in[0];
    const int*   labels = (const int*)d_in[1];
    const float* window = (const float*)d_in[2];
    const int L = in_sizes[2];

    float* out = (float*)d_out;
    float* rl  = (float*)d_ws;   // 4096 floats of per-row loss (written every call)

    row_loss_kernel<<<BROWS, TPB, 0, stream>>>(preds, labels, window, L, rl);
    reduce_kernel<<<1, 256, 0, stream>>>(rl, out, BROWS);
}